// Round 11
// baseline (58785.602 us; speedup 1.0000x reference)
//
#include <hip/hip_runtime.h>
#include <math.h>

#define NROWS 4096
#define DZ    128
#define DH    512
#define VOC   64
#define DE    128
#define MAXLEN 128
#define PAD_T 0
#define SOS_T 1
#define EOS_T 2

typedef __attribute__((ext_vector_type(8))) _Float16 f16x8;  // 8 f16 (4 VGPRs)
typedef __attribute__((ext_vector_type(4))) float f32x4;

__device__ __forceinline__ unsigned short hbits(_Float16 h) {
  return __builtin_bit_cast(unsigned short, h);
}
__device__ __forceinline__ f32x4 mfma_f16(f16x8 a, f16x8 b, f32x4 c) {
  return __builtin_amdgcn_mfma_f32_16x16x32_f16(a, b, c, 0, 0, 0);
}
#define GLD16(gp, lp)                                                        \
  __builtin_amdgcn_global_load_lds(                                          \
      (const __attribute__((address_space(1))) unsigned int*)(gp),           \
      (__attribute__((address_space(3))) unsigned int*)(lp), 16, 0, 0)

// ---------------- transpose: in [R][C] -> out [C][R] ----------------
__global__ void transpose_k(const float* __restrict__ in, float* __restrict__ out,
                            int R, int C) {
  __shared__ float tile[32][33];
  int cb = blockIdx.x * 32, rb = blockIdx.y * 32;
  int tx = threadIdx.x, ty = threadIdx.y;  // blockDim (32,8)
  #pragma unroll
  for (int i = ty; i < 32; i += 8)
    tile[i][tx] = in[(size_t)(rb + i) * C + (cb + tx)];
  __syncthreads();
  #pragma unroll
  for (int i = ty; i < 32; i += 8)
    out[(size_t)(cb + i) * R + (rb + tx)] = tile[tx][i];
}

// ---------------- repack h2v: in [Rn][K] -> P[((k>>2)*Rn + r)*4 + (k&3)] -----
__global__ void repack_k(const float* __restrict__ in, float* __restrict__ out,
                         int Rn, int K) {
  int k = blockIdx.y * 128 + threadIdx.x;
  int r = blockIdx.x;
  out[((size_t)(k >> 2) * Rn + r) * 4 + (k & 3)] = in[(size_t)r * K + k];
}

// ---- pack weights to 2-limb fp16 B-fragments (m-limb scaled by 2^11) -------
// W [3*DH][512] fp32 -> out[g][l][nt][kc][lane][j] f16
__global__ void pack_w2(const float* __restrict__ W, unsigned short* __restrict__ out) {
  size_t i = (size_t)blockIdx.x * 256 + threadIdx.x;  // total 6*32*16*512
  int j = (int)(i & 7);
  int lane = (int)((i >> 3) & 63);
  size_t t = i >> 9;
  int kc = (int)(t & 15); t >>= 4;
  int nt = (int)(t & 31); t >>= 5;
  int l = (int)(t & 1);
  int g = (int)(t >> 1);
  int n = nt * 16 + (lane & 15);
  int k = kc * 32 + (lane >> 4) * 8 + j;
  float w = W[(size_t)(g * DH + n) * DH + k];
  _Float16 wh = (_Float16)w;
  float fh = (float)wh;
  _Float16 wm = (_Float16)((w - fh) * 2048.0f);
  out[i] = hbits(l == 0 ? wh : wm);
}

// ---------------- G0[v][jj] = sum_k emb[v][k] * WiT0[k][jj] + bi[jj] ---------
__global__ __launch_bounds__(256) void build_g0(
    const float* __restrict__ emb, const float* __restrict__ WiT0,
    const float* __restrict__ bi, float* __restrict__ G0) {
  int jj = blockIdx.y * 256 + threadIdx.x;   // grid.y = 3*DH/256
  int v = blockIdx.x;                        // grid.x = VOC
  float acc = bi[jj];
  const float* e = emb + (size_t)v * DE;     // wave-uniform -> s_load
  #pragma unroll 4
  for (int k = 0; k < DE; ++k)
    acc = fmaf(e[k], WiT0[(size_t)k * (3 * DH) + jj], acc);
  G0[(size_t)v * (3 * DH) + jj] = acc;
}

// ---------------- init: h0 = Z @ z2h_w^T + b; 2-limb + f32 state init --------
__global__ __launch_bounds__(256) void init_kernel(
    const float* __restrict__ Z, const float* __restrict__ z2hT,
    const float* __restrict__ z2h_b,
    unsigned short* __restrict__ h1H, unsigned short* __restrict__ h1M, float* __restrict__ f1,
    unsigned short* __restrict__ h2H, unsigned short* __restrict__ h2M, float* __restrict__ f2,
    unsigned short* __restrict__ h3H, unsigned short* __restrict__ h3M, float* __restrict__ f3,
    int* __restrict__ tok, int* __restrict__ eos, int* __restrict__ outi) {
  int lane = threadIdx.x & 63;
  int wave = __builtin_amdgcn_readfirstlane((int)(threadIdx.x >> 6));
  int r = blockIdx.x * 4 + wave;          // grid.x = NROWS/4
  int j = blockIdx.y * 64 + lane;         // grid.y = DH/64
  float acc = z2h_b[j];
  const float* zr = Z + (size_t)r * DZ;   // wave-uniform -> s_load
  #pragma unroll 4
  for (int k = 0; k < DZ; ++k)
    acc = fmaf(zr[k], z2hT[(size_t)k * DH + j], acc);
  size_t o = (size_t)r * DH + j;
  _Float16 uh = (_Float16)acc;
  float fh = (float)uh;
  _Float16 um = (_Float16)((acc - fh) * 2048.0f);
  unsigned short bh_ = hbits(uh), bm_ = hbits(um);
  h1H[o] = bh_; h1M[o] = bm_; f1[o] = acc;
  h2H[o] = bh_; h2M[o] = bm_; f2[o] = acc;
  h3H[o] = bh_; h3M[o] = bm_; f3[o] = acc;
  if (blockIdx.y == 0 && lane == 0) {
    tok[r] = SOS_T;
    eos[r] = 0;
    outi[(size_t)r * MAXLEN] = SOS_T;               // X_gen[:,0] = SOS
    outi[(size_t)NROWS * MAXLEN + r] = MAXLEN;      // seq_lens init
  }
}

// ---- compute one staged chunk (CNT kc): acc += A-limbs x B-limbs -----------
// NPL = plane for gate 2 (2 = i_n, 3 = h_n), compile-time.
template <int NPL, int CNT>
__device__ __forceinline__ void chunk_compute(
    const unsigned short* __restrict__ S,
    const unsigned short* __restrict__ AH,
    const unsigned short* __restrict__ AM,
    int kc0, int m0, int col, int quad, int lane,
    f32x4 (&accH)[2][4], f32x4 (&accC)[2][4]) {
  #pragma unroll
  for (int kc2 = 0; kc2 < CNT; ++kc2) {
    int kc = kc0 + kc2;
    f16x8 a0[2], a1[2];
    #pragma unroll
    for (int mt = 0; mt < 2; ++mt) {
      size_t ao = (size_t)(m0 + mt * 16 + col) * DH + kc * 32 + quad * 8;
      a0[mt] = *(const f16x8*)(AH + ao);
      a1[mt] = *(const f16x8*)(AM + ao);
    }
    #pragma unroll
    for (int g = 0; g < 3; ++g) {
      const unsigned short* bp = S + (size_t)(kc2 * 6 + g * 2) * 512 + lane * 8;
      f16x8 b0 = *(const f16x8*)(bp);            // limb h
      f16x8 b1 = *(const f16x8*)(bp + 512);      // limb m (x2048)
      int pl = (g == 2) ? NPL : g;               // const-folded per unrolled g
      #pragma unroll
      for (int mt = 0; mt < 2; ++mt) {
        accC[mt][pl] = mfma_f16(a1[mt], b0, accC[mt][pl]);  // am*wh
        accC[mt][pl] = mfma_f16(a0[mt], b1, accC[mt][pl]);  // ah*wm
        accH[mt][pl] = mfma_f16(a0[mt], b0, accH[mt][pl]);  // ah*wh
      }
    }
  }
}

// ---------------- fused GRU layer: fp16 2-limb MFMA + LDS-staged B ----------
// wg = 4 waves sharing one j-tile; wave tile = 32 rows x 16 j x 3 gates.
// Unified chunk pipeline across Wi->Wh; variable chunks {3,3,3,3,2,2} kc per
// phase -> 13 barriers (vs 18). 36 KB ping-pong LDS, 4 wgs/CU.
template <bool IS_L0>
__global__ __launch_bounds__(256, 4) void gru_mfma(
    const unsigned short* __restrict__ XH, const unsigned short* __restrict__ XM,
    const unsigned short* __restrict__ HH, const unsigned short* __restrict__ HM,
    const float* __restrict__ Fin,           // prev h fp32 (blend)
    const unsigned short* __restrict__ WiPk, const unsigned short* __restrict__ WhPk,
    const int* __restrict__ tok, const float* __restrict__ G0,
    const float* __restrict__ bi, const float* __restrict__ bh,
    unsigned short* __restrict__ OH, unsigned short* __restrict__ OM,
    float* __restrict__ Fout) {
  __shared__ __attribute__((aligned(16))) unsigned short ldsB[2][18 * 512]; // 36 KB
  const int tid  = threadIdx.x;
  const int lane = tid & 63;
  const int wave = __builtin_amdgcn_readfirstlane(tid >> 6);
  const int wg = blockIdx.x;
  const int ntile = wg & 31;           // j-tile
  const int rblk = wg >> 5;            // row block; grid.x = (NROWS/128)*32
  const int m0 = rblk * 128 + wave * 32;
  const int col = lane & 15, quad = lane >> 4;
  const int jc = ntile * 16 + col;
  constexpr int NCH = IS_L0 ? 6 : 12;

  f32x4 accH[2][4], accC[2][4];        // [mt][plane: r,z,in,hn]
  #pragma unroll
  for (int mt = 0; mt < 2; ++mt)
    #pragma unroll
    for (int p = 0; p < 4; ++p) {
      accH[mt][p] = (f32x4){0.f, 0.f, 0.f, 0.f};
      accC[mt][p] = (f32x4){0.f, 0.f, 0.f, 0.f};
    }

  // prefetch epilogue fp32 prev-state (loads issue now, consumed at end)
  float fpre[2][4];
  #pragma unroll
  for (int mt = 0; mt < 2; ++mt)
    #pragma unroll
    for (int i = 0; i < 4; ++i)
      fpre[mt][i] = Fin[(size_t)(m0 + mt * 16 + quad * 4 + i) * DH + jc];

  // stage chunk c into ldsB[buf]; segs (kci*6 + g*2 + l) split over 4 waves
  auto stage = [&](int c, int buf) {
    int lc = (!IS_L0 && c >= 6) ? c - 6 : c;
    const unsigned short* Wp = (!IS_L0 && c < 6) ? WiPk : WhPk;
    int kc0 = (lc < 4) ? lc * 3 : 12 + (lc - 4) * 2;
    int nseg = ((lc < 4) ? 3 : 2) * 6;
    for (int s = wave; s < nseg; s += 4) {
      int kci = s / 6, gl = s - 6 * kci;
      const unsigned short* src =
          Wp + (((size_t)gl * 32 + ntile) * 16 + (kc0 + kci)) * 512 + lane * 8;
      GLD16(src, &ldsB[buf][(size_t)s * 512]);
    }
  };

  stage(0, 0);
  for (int c = 0; c < NCH; ++c) {
    __syncthreads();                       // drains staging of chunk c
    if (c + 1 < NCH) stage(c + 1, (c + 1) & 1);
    const unsigned short* S = ldsB[c & 1];
    bool isWi = (!IS_L0 && c < 6);
    int lc = isWi ? c : (IS_L0 ? c : c - 6);
    const unsigned short* AH_ = isWi ? XH : HH;
    const unsigned short* AM_ = isWi ? XM : HM;
    int kc0 = (lc < 4) ? lc * 3 : 12 + (lc - 4) * 2;
    if (isWi) {
      if (lc < 4) chunk_compute<2, 3>(S, AH_, AM_, kc0, m0, col, quad, lane, accH, accC);
      else        chunk_compute<2, 2>(S, AH_, AM_, kc0, m0, col, quad, lane, accH, accC);
    } else {
      if (lc < 4) chunk_compute<3, 3>(S, AH_, AM_, kc0, m0, col, quad, lane, accH, accC);
      else        chunk_compute<3, 2>(S, AH_, AM_, kc0, m0, col, quad, lane, accH, accC);
    }
  }

  float bhr = bh[jc], bhz = bh[DH + jc], bhn = bh[2 * DH + jc];
  float bir = 0.f, biz = 0.f, bin = 0.f;
  if constexpr (!IS_L0) { bir = bi[jc]; biz = bi[DH + jc]; bin = bi[2 * DH + jc]; }
  const float IS = 1.0f / 2048.0f;

  #pragma unroll
  for (int mt = 0; mt < 2; ++mt) {
    #pragma unroll
    for (int i = 0; i < 4; ++i) {
      int row = m0 + mt * 16 + quad * 4 + i;
      float gr = accH[mt][0][i] + IS * accC[mt][0][i] + bhr;
      float gz = accH[mt][1][i] + IS * accC[mt][1][i] + bhz;
      float gin = accH[mt][2][i] + IS * accC[mt][2][i];
      float ghn = accH[mt][3][i] + IS * accC[mt][3][i] + bhn;
      if constexpr (IS_L0) {
        const float* g0p = G0 + (size_t)tok[row] * (3 * DH);
        gr += g0p[jc]; gz += g0p[DH + jc]; gin += g0p[2 * DH + jc];
      } else {
        gr += bir; gz += biz; gin += bin;
      }
      float rg = 1.f / (1.f + expf(-gr));
      float zg = 1.f / (1.f + expf(-gz));
      float nn = tanhf(gin + rg * ghn);
      size_t ho = (size_t)row * DH + jc;
      float hp = fpre[mt][i];                   // exact fp32 prev state
      float hv = (1.f - zg) * nn + zg * hp;
      _Float16 uh = (_Float16)hv;
      float fh = (float)uh;
      _Float16 um = (_Float16)((hv - fh) * 2048.0f);
      OH[ho] = hbits(uh); OM[ho] = hbits(um);
      Fout[ho] = hv;
    }
  }
}

// ---------------- logits + argmax + EOS bookkeeping ----------------
__global__ __launch_bounds__(256) void argmax_kernel(
    const float* __restrict__ H3, const float* __restrict__ h2vP,
    const float* __restrict__ h2v_b,
    int* __restrict__ tok, int* __restrict__ eos,
    int* __restrict__ outi, int t) {
  int lane = threadIdx.x & 63;
  int wave = __builtin_amdgcn_readfirstlane((int)(threadIdx.x >> 6));
  int r0 = blockIdx.x * 16 + wave * 4;    // grid.x = NROWS/16
  float acc[4];
  float b = h2v_b[lane];
  #pragma unroll
  for (int i = 0; i < 4; ++i) acc[i] = b;
  const float4* w4 = (const float4*)h2vP;
  const float4* h4[4];
  #pragma unroll
  for (int i = 0; i < 4; ++i)
    h4[i] = (const float4*)(H3 + (size_t)(r0 + i) * DH);
  #pragma unroll 2
  for (int k4 = 0; k4 < DH / 4; ++k4) {
    float4 w = w4[(size_t)k4 * VOC + lane];       // coalesced vector
    #pragma unroll
    for (int i = 0; i < 4; ++i) {
      float4 h = h4[i][k4];                        // wave-uniform -> s_load
      acc[i] = fmaf(h.x, w.x, acc[i]); acc[i] = fmaf(h.y, w.y, acc[i]);
      acc[i] = fmaf(h.z, w.z, acc[i]); acc[i] = fmaf(h.w, w.w, acc[i]);
    }
  }
  #pragma unroll
  for (int i = 0; i < 4; ++i) {
    float v = acc[i]; int idx = lane;
    #pragma unroll
    for (int off = 32; off >= 1; off >>= 1) {
      float v2 = __shfl_xor(v, off);
      int   i2 = __shfl_xor(idx, off);
      if (v2 > v || (v2 == v && i2 < idx)) { v = v2; idx = i2; }
    }
    if (lane == 0) {
      int r = r0 + i;
      int e = eos[r];
      int x_next = idx;
      outi[(size_t)r * MAXLEN + t] = e ? PAD_T : x_next;
      if (!e && x_next == EOS_T) {
        outi[(size_t)NROWS * MAXLEN + r] = t + 1;  // seq_lens
        eos[r] = 1;
      }
      tok[r] = x_next;
    }
  }
}

// ---------------- host-side orchestration ----------------
extern "C" void kernel_launch(void* const* d_in, const int* in_sizes, int n_in,
                              void* d_out, int out_size, void* d_ws, size_t ws_size,
                              hipStream_t stream) {
  const float* Z      = (const float*)d_in[0];
  const float* emb    = (const float*)d_in[1];
  const float* z2h_w  = (const float*)d_in[2];
  const float* z2h_b  = (const float*)d_in[3];
  const float* W_ih0  = (const float*)d_in[4];
  const float* W_hh0  = (const float*)d_in[5];
  const float* b_ih0  = (const float*)d_in[6];
  const float* b_hh0  = (const float*)d_in[7];
  const float* W_ih1  = (const float*)d_in[8];
  const float* W_hh1  = (const float*)d_in[9];
  const float* b_ih1  = (const float*)d_in[10];
  const float* b_hh1  = (const float*)d_in[11];
  const float* W_ih2  = (const float*)d_in[12];
  const float* W_hh2  = (const float*)d_in[13];
  const float* b_ih2  = (const float*)d_in[14];
  const float* b_hh2  = (const float*)d_in[15];
  const float* h2v_w  = (const float*)d_in[16];
  const float* h2v_b  = (const float*)d_in[17];
  int* outi = (int*)d_out;

  const size_t PKS = (size_t)6 * 32 * 16 * 512;   // ushorts per packed matrix
  const size_t PLN = (size_t)NROWS * DH;          // elems per state plane

  unsigned short* us = (unsigned short*)d_ws;
  unsigned short* Wh0P = us; us += PKS;
  unsigned short* Wi1P = us; us += PKS;
  unsigned short* Wh1P = us; us += PKS;
  unsigned short* Wi2P = us; us += PKS;
  unsigned short* Wh2P = us; us += PKS;
  // fp16 limb planes: [layer][buf][limb]
  unsigned short* L[3][2][2];
  for (int ly = 0; ly < 3; ++ly)
    for (int bu = 0; bu < 2; ++bu)
      for (int li = 0; li < 2; ++li) { L[ly][bu][li] = us; us += PLN; }
  float* p = (float*)us;
  // fp32 state planes: [layer][buf]
  float* F[3][2];
  for (int ly = 0; ly < 3; ++ly)
    for (int bu = 0; bu < 2; ++bu) { F[ly][bu] = p; p += PLN; }
  float* WiT0 = p; p += (size_t)DE * 3 * DH;
  float* G0   = p; p += (size_t)VOC * 3 * DH;
  float* z2hT = p; p += (size_t)DZ * DH;
  float* h2vP = p; p += (size_t)DH * VOC;
  int* tokb = (int*)p;
  int* eosb = tokb + NROWS;

  // one-time prep
  {
    int nblk = (int)(PKS / 256);
    pack_w2<<<nblk, 256, 0, stream>>>(W_hh0, Wh0P);
    pack_w2<<<nblk, 256, 0, stream>>>(W_ih1, Wi1P);
    pack_w2<<<nblk, 256, 0, stream>>>(W_hh1, Wh1P);
    pack_w2<<<nblk, 256, 0, stream>>>(W_ih2, Wi2P);
    pack_w2<<<nblk, 256, 0, stream>>>(W_hh2, Wh2P);
  }
  transpose_k<<<dim3(DE / 32, (3 * DH) / 32), dim3(32, 8), 0, stream>>>(
      W_ih0, WiT0, 3 * DH, DE);
  transpose_k<<<dim3(DZ / 32, DH / 32), dim3(32, 8), 0, stream>>>(
      z2h_w, z2hT, DH, DZ);
  repack_k<<<dim3(VOC, DH / 128), 128, 0, stream>>>(h2v_w, h2vP, VOC, DH);
  build_g0<<<dim3(VOC, (3 * DH) / 256), 256, 0, stream>>>(emb, WiT0, b_ih0, G0);

  init_kernel<<<dim3(NROWS / 4, DH / 64), 256, 0, stream>>>(
      Z, z2hT, z2h_b,
      L[0][0][0], L[0][0][1], F[0][0],
      L[1][0][0], L[1][0][1], F[1][0],
      L[2][0][0], L[2][0][1], F[2][0],
      tokb, eosb, outi);

  const int ggrid = (NROWS / 128) * 32;   // 1024 wgs, 4 per CU
  int cur = 0;
  for (int t = 1; t < MAXLEN; ++t) {
    int nxt = cur ^ 1;
    gru_mfma<true><<<ggrid, 256, 0, stream>>>(
        nullptr, nullptr,
        L[0][cur][0], L[0][cur][1], F[0][cur],
        nullptr, Wh0P, tokb, G0, nullptr, b_hh0,
        L[0][nxt][0], L[0][nxt][1], F[0][nxt]);
    gru_mfma<false><<<ggrid, 256, 0, stream>>>(
        L[0][nxt][0], L[0][nxt][1],
        L[1][cur][0], L[1][cur][1], F[1][cur],
        Wi1P, Wh1P, nullptr, nullptr, b_ih1, b_hh1,
        L[1][nxt][0], L[1][nxt][1], F[1][nxt]);
    gru_mfma<false><<<ggrid, 256, 0, stream>>>(
        L[1][nxt][0], L[1][nxt][1],
        L[2][cur][0], L[2][cur][1], F[2][cur],
        Wi2P, Wh2P, nullptr, nullptr, b_ih2, b_hh2,
        L[2][nxt][0], L[2][nxt][1], F[2][nxt]);
    argmax_kernel<<<dim3(NROWS / 16), 256, 0, stream>>>(
        F[2][nxt], h2vP, h2v_b, tokb, eosb, outi, t);
    cur = nxt;
  }
}

// Round 12
// 21953.125 us; speedup vs baseline: 2.6778x; 2.6778x over previous
//
#include <hip/hip_runtime.h>
#include <math.h>

#define NROWS 4096
#define DZ    128
#define DH    512
#define VOC   64
#define DE    128
#define MAXLEN 128
#define PAD_T 0
#define SOS_T 1
#define EOS_T 2

typedef __attribute__((ext_vector_type(8))) _Float16 f16x8;  // 8 f16 (4 VGPRs)
typedef __attribute__((ext_vector_type(4))) float f32x4;

__device__ __forceinline__ unsigned short hbits(_Float16 h) {
  return __builtin_bit_cast(unsigned short, h);
}
__device__ __forceinline__ f32x4 mfma_f16(f16x8 a, f16x8 b, f32x4 c) {
  return __builtin_amdgcn_mfma_f32_16x16x32_f16(a, b, c, 0, 0, 0);
}
#define GLD16(gp, lp)                                                        \
  __builtin_amdgcn_global_load_lds(                                          \
      (const __attribute__((address_space(1))) unsigned int*)(gp),           \
      (__attribute__((address_space(3))) unsigned int*)(lp), 16, 0, 0)

// A-fragment-major layout for activation limb planes:
// element (row, k) lives at ((row>>4)*16 + (k>>5))*512 + ((row&15) + 16*((k>>3)&3))*8 + (k&7)
__device__ __forceinline__ size_t PIDX(int row, int k) {
  return ((size_t)((row >> 4) * 16 + (k >> 5))) * 512 +
         (size_t)(((row & 15) + 16 * ((k >> 3) & 3)) * 8 + (k & 7));
}

// ---------------- transpose: in [R][C] -> out [C][R] ----------------
__global__ void transpose_k(const float* __restrict__ in, float* __restrict__ out,
                            int R, int C) {
  __shared__ float tile[32][33];
  int cb = blockIdx.x * 32, rb = blockIdx.y * 32;
  int tx = threadIdx.x, ty = threadIdx.y;  // blockDim (32,8)
  #pragma unroll
  for (int i = ty; i < 32; i += 8)
    tile[i][tx] = in[(size_t)(rb + i) * C + (cb + tx)];
  __syncthreads();
  #pragma unroll
  for (int i = ty; i < 32; i += 8)
    out[(size_t)(cb + i) * R + (rb + tx)] = tile[tx][i];
}

// ---------------- repack h2v: in [Rn][K] -> P[((k>>2)*Rn + r)*4 + (k&3)] -----
__global__ void repack_k(const float* __restrict__ in, float* __restrict__ out,
                         int Rn, int K) {
  int k = blockIdx.y * 128 + threadIdx.x;
  int r = blockIdx.x;
  out[((size_t)(k >> 2) * Rn + r) * 4 + (k & 3)] = in[(size_t)r * K + k];
}

// ---- pack weights to 2-limb fp16 B-fragments (m-limb scaled by 2^11) -------
// W [3*DH][512] fp32 -> out[g][l][nt][kc][lane][j] f16
__global__ void pack_w2(const float* __restrict__ W, unsigned short* __restrict__ out) {
  size_t i = (size_t)blockIdx.x * 256 + threadIdx.x;  // total 6*32*16*512
  int j = (int)(i & 7);
  int lane = (int)((i >> 3) & 63);
  size_t t = i >> 9;
  int kc = (int)(t & 15); t >>= 4;
  int nt = (int)(t & 31); t >>= 5;
  int l = (int)(t & 1);
  int g = (int)(t >> 1);
  int n = nt * 16 + (lane & 15);
  int k = kc * 32 + (lane >> 4) * 8 + j;
  float w = W[(size_t)(g * DH + n) * DH + k];
  _Float16 wh = (_Float16)w;
  float fh = (float)wh;
  _Float16 wm = (_Float16)((w - fh) * 2048.0f);
  out[i] = hbits(l == 0 ? wh : wm);
}

// ---------------- G0[v][jj] = sum_k emb[v][k] * WiT0[k][jj] + bi[jj] ---------
__global__ __launch_bounds__(256) void build_g0(
    const float* __restrict__ emb, const float* __restrict__ WiT0,
    const float* __restrict__ bi, float* __restrict__ G0) {
  int jj = blockIdx.y * 256 + threadIdx.x;   // grid.y = 3*DH/256
  int v = blockIdx.x;                        // grid.x = VOC
  float acc = bi[jj];
  const float* e = emb + (size_t)v * DE;     // wave-uniform -> s_load
  #pragma unroll 4
  for (int k = 0; k < DE; ++k)
    acc = fmaf(e[k], WiT0[(size_t)k * (3 * DH) + jj], acc);
  G0[(size_t)v * (3 * DH) + jj] = acc;
}

// ---------------- init: h0 = Z @ z2h_w^T + b; 2-limb + f32 state init --------
__global__ __launch_bounds__(256) void init_kernel(
    const float* __restrict__ Z, const float* __restrict__ z2hT,
    const float* __restrict__ z2h_b,
    unsigned short* __restrict__ h1H, unsigned short* __restrict__ h1M, float* __restrict__ f1,
    unsigned short* __restrict__ h2H, unsigned short* __restrict__ h2M, float* __restrict__ f2,
    unsigned short* __restrict__ h3H, unsigned short* __restrict__ h3M, float* __restrict__ f3,
    int* __restrict__ tok, int* __restrict__ eos, int* __restrict__ outi) {
  int lane = threadIdx.x & 63;
  int wave = __builtin_amdgcn_readfirstlane((int)(threadIdx.x >> 6));
  int r = blockIdx.x * 4 + wave;          // grid.x = NROWS/4
  int j = blockIdx.y * 64 + lane;         // grid.y = DH/64
  float acc = z2h_b[j];
  const float* zr = Z + (size_t)r * DZ;   // wave-uniform -> s_load
  #pragma unroll 4
  for (int k = 0; k < DZ; ++k)
    acc = fmaf(zr[k], z2hT[(size_t)k * DH + j], acc);
  size_t o = (size_t)r * DH + j;          // fp32 plane: plain layout
  size_t op = PIDX(r, j);                 // limb planes: fragment layout
  _Float16 uh = (_Float16)acc;
  float fh = (float)uh;
  _Float16 um = (_Float16)((acc - fh) * 2048.0f);
  unsigned short bh_ = hbits(uh), bm_ = hbits(um);
  h1H[op] = bh_; h1M[op] = bm_; f1[o] = acc;
  h2H[op] = bh_; h2M[op] = bm_; f2[o] = acc;
  h3H[op] = bh_; h3M[op] = bm_; f3[o] = acc;
  if (blockIdx.y == 0 && lane == 0) {
    tok[r] = SOS_T;
    eos[r] = 0;
    outi[(size_t)r * MAXLEN] = SOS_T;               // X_gen[:,0] = SOS
    outi[(size_t)NROWS * MAXLEN + r] = MAXLEN;      // seq_lens init
  }
}

// ---------------- fused GRU layer: fp16 2-limb MFMA + LDS-staged B ----------
// wg = 4 waves sharing one j-tile; wave tile = 32 rows x 16 j x 3 gates.
// B: global->LDS (GLD16) ping-pong 2-kc chunks. A: fragment-major limb planes
// -> one coalesced 1KB wave load per (mt,kc,limb).
template <bool IS_L0>
__global__ __launch_bounds__(256, 4) void gru_mfma(
    const unsigned short* __restrict__ XH, const unsigned short* __restrict__ XM,
    const unsigned short* __restrict__ HH, const unsigned short* __restrict__ HM,
    const float* __restrict__ Fin,           // prev h fp32 (blend), plain layout
    const unsigned short* __restrict__ WiPk, const unsigned short* __restrict__ WhPk,
    const int* __restrict__ tok, const float* __restrict__ G0,
    const float* __restrict__ bi, const float* __restrict__ bh,
    unsigned short* __restrict__ OH, unsigned short* __restrict__ OM,
    float* __restrict__ Fout) {
  __shared__ __attribute__((aligned(16))) unsigned short ldsB[2][12 * 512]; // 24 KB
  const int tid  = threadIdx.x;
  const int lane = tid & 63;
  const int wave = __builtin_amdgcn_readfirstlane(tid >> 6);
  const int wg = blockIdx.x;
  const int ntile = wg & 31;           // j-tile
  const int rblk = wg >> 5;            // row block
  const int m0 = rblk * 128 + wave * 32;
  const int rt0 = (m0 >> 4);           // row-tile index for A-fragment layout
  const int col = lane & 15, quad = lane >> 4;
  const int jc = ntile * 16 + col;

  f32x4 accH[2][4], accC[2][4];        // [mt][plane: r,z,in,hn]
  #pragma unroll
  for (int mt = 0; mt < 2; ++mt)
    #pragma unroll
    for (int p = 0; p < 4; ++p) {
      accH[mt][p] = (f32x4){0.f, 0.f, 0.f, 0.f};
      accC[mt][p] = (f32x4){0.f, 0.f, 0.f, 0.f};
    }

  // stage chunk c (kc = 2c, 2c+1): 12 segs (kc2*6 + g*2 + l), split over waves
  auto stage = [&](const unsigned short* Wp, int c, int buf) {
    for (int s = wave; s < 12; s += 4) {
      int kc2 = s / 6, gl = s - 6 * kc2;
      const unsigned short* src =
          Wp + (((size_t)gl * 32 + ntile) * 16 + (c * 2 + kc2)) * 512 + lane * 8;
      GLD16(src, &ldsB[buf][(size_t)s * 512]);
    }
  };

  auto phase = [&](const unsigned short* AH, const unsigned short* AM,
                   const unsigned short* Wp, int nplane) {
    stage(Wp, 0, 0);
    for (int c = 0; c < 8; ++c) {
      __syncthreads();                       // drains staging of chunk c
      if (c + 1 < 8) stage(Wp, c + 1, (c + 1) & 1);
      const unsigned short* S = ldsB[c & 1];
      #pragma unroll
      for (int kc2 = 0; kc2 < 2; ++kc2) {
        int kc = c * 2 + kc2;
        f16x8 a0[2], a1[2];
        #pragma unroll
        for (int mt = 0; mt < 2; ++mt) {
          // fragment-major: one coalesced 1KB wave load per limb
          size_t ao = ((size_t)(rt0 + mt) * 16 + kc) * 512 + (size_t)lane * 8;
          a0[mt] = *(const f16x8*)(AH + ao);
          a1[mt] = *(const f16x8*)(AM + ao);
        }
        #pragma unroll
        for (int g = 0; g < 3; ++g) {
          const unsigned short* bp = S + (size_t)(kc2 * 6 + g * 2) * 512 + lane * 8;
          f16x8 b0 = *(const f16x8*)(bp);            // limb h
          f16x8 b1 = *(const f16x8*)(bp + 512);      // limb m (x2048)
          int pl = (g == 2) ? nplane : g;
          #pragma unroll
          for (int mt = 0; mt < 2; ++mt) {
            accC[mt][pl] = mfma_f16(a1[mt], b0, accC[mt][pl]);  // am*wh
            accC[mt][pl] = mfma_f16(a0[mt], b1, accC[mt][pl]);  // ah*wm
            accH[mt][pl] = mfma_f16(a0[mt], b0, accH[mt][pl]);  // ah*wh
          }
        }
      }
    }
    __syncthreads();                           // protect LDS before next phase
  };

  if constexpr (!IS_L0)
    phase(XH, XM, WiPk, 2);
  phase(HH, HM, WhPk, 3);

  float bhr = bh[jc], bhz = bh[DH + jc], bhn = bh[2 * DH + jc];
  float bir = 0.f, biz = 0.f, bin = 0.f;
  if constexpr (!IS_L0) { bir = bi[jc]; biz = bi[DH + jc]; bin = bi[2 * DH + jc]; }
  const float IS = 1.0f / 2048.0f;

  #pragma unroll
  for (int mt = 0; mt < 2; ++mt) {
    #pragma unroll
    for (int i = 0; i < 4; ++i) {
      int row = m0 + mt * 16 + quad * 4 + i;
      float gr = accH[mt][0][i] + IS * accC[mt][0][i] + bhr;
      float gz = accH[mt][1][i] + IS * accC[mt][1][i] + bhz;
      float gin = accH[mt][2][i] + IS * accC[mt][2][i];
      float ghn = accH[mt][3][i] + IS * accC[mt][3][i] + bhn;
      if constexpr (IS_L0) {
        const float* g0p = G0 + (size_t)tok[row] * (3 * DH);
        gr += g0p[jc]; gz += g0p[DH + jc]; gin += g0p[2 * DH + jc];
      } else {
        gr += bir; gz += biz; gin += bin;
      }
      float rg = 1.f / (1.f + expf(-gr));
      float zg = 1.f / (1.f + expf(-gz));
      float nn = tanhf(gin + rg * ghn);
      size_t ho = (size_t)row * DH + jc;        // fp32 plane: plain
      float hp = Fin[ho];                       // exact fp32 prev state
      float hv = (1.f - zg) * nn + zg * hp;
      _Float16 uh = (_Float16)hv;
      float fh = (float)uh;
      _Float16 um = (_Float16)((hv - fh) * 2048.0f);
      size_t hop = PIDX(row, jc);               // limb planes: fragment layout
      OH[hop] = hbits(uh); OM[hop] = hbits(um);
      Fout[ho] = hv;
    }
  }
}

// ---------------- logits + argmax + EOS bookkeeping ----------------
__global__ __launch_bounds__(256) void argmax_kernel(
    const float* __restrict__ H3, const float* __restrict__ h2vP,
    const float* __restrict__ h2v_b,
    int* __restrict__ tok, int* __restrict__ eos,
    int* __restrict__ outi, int t) {
  int lane = threadIdx.x & 63;
  int wave = __builtin_amdgcn_readfirstlane((int)(threadIdx.x >> 6));
  int r0 = blockIdx.x * 16 + wave * 4;    // grid.x = NROWS/16
  float acc[4];
  float b = h2v_b[lane];
  #pragma unroll
  for (int i = 0; i < 4; ++i) acc[i] = b;
  const float4* w4 = (const float4*)h2vP;
  const float4* h4[4];
  #pragma unroll
  for (int i = 0; i < 4; ++i)
    h4[i] = (const float4*)(H3 + (size_t)(r0 + i) * DH);
  #pragma unroll 2
  for (int k4 = 0; k4 < DH / 4; ++k4) {
    float4 w = w4[(size_t)k4 * VOC + lane];       // coalesced vector
    #pragma unroll
    for (int i = 0; i < 4; ++i) {
      float4 h = h4[i][k4];                        // wave-uniform -> s_load
      acc[i] = fmaf(h.x, w.x, acc[i]); acc[i] = fmaf(h.y, w.y, acc[i]);
      acc[i] = fmaf(h.z, w.z, acc[i]); acc[i] = fmaf(h.w, w.w, acc[i]);
    }
  }
  #pragma unroll
  for (int i = 0; i < 4; ++i) {
    float v = acc[i]; int idx = lane;
    #pragma unroll
    for (int off = 32; off >= 1; off >>= 1) {
      float v2 = __shfl_xor(v, off);
      int   i2 = __shfl_xor(idx, off);
      if (v2 > v || (v2 == v && i2 < idx)) { v = v2; idx = i2; }
    }
    if (lane == 0) {
      int r = r0 + i;
      int e = eos[r];
      int x_next = idx;
      outi[(size_t)r * MAXLEN + t] = e ? PAD_T : x_next;
      if (!e && x_next == EOS_T) {
        outi[(size_t)NROWS * MAXLEN + r] = t + 1;  // seq_lens
        eos[r] = 1;
      }
      tok[r] = x_next;
    }
  }
}

// ---------------- host-side orchestration ----------------
extern "C" void kernel_launch(void* const* d_in, const int* in_sizes, int n_in,
                              void* d_out, int out_size, void* d_ws, size_t ws_size,
                              hipStream_t stream) {
  const float* Z      = (const float*)d_in[0];
  const float* emb    = (const float*)d_in[1];
  const float* z2h_w  = (const float*)d_in[2];
  const float* z2h_b  = (const float*)d_in[3];
  const float* W_ih0  = (const float*)d_in[4];
  const float* W_hh0  = (const float*)d_in[5];
  const float* b_ih0  = (const float*)d_in[6];
  const float* b_hh0  = (const float*)d_in[7];
  const float* W_ih1  = (const float*)d_in[8];
  const float* W_hh1  = (const float*)d_in[9];
  const float* b_ih1  = (const float*)d_in[10];
  const float* b_hh1  = (const float*)d_in[11];
  const float* W_ih2  = (const float*)d_in[12];
  const float* W_hh2  = (const float*)d_in[13];
  const float* b_ih2  = (const float*)d_in[14];
  const float* b_hh2  = (const float*)d_in[15];
  const float* h2v_w  = (const float*)d_in[16];
  const float* h2v_b  = (const float*)d_in[17];
  int* outi = (int*)d_out;

  const size_t PKS = (size_t)6 * 32 * 16 * 512;   // ushorts per packed matrix
  const size_t PLN = (size_t)NROWS * DH;          // elems per state plane

  unsigned short* us = (unsigned short*)d_ws;
  unsigned short* Wh0P = us; us += PKS;
  unsigned short* Wi1P = us; us += PKS;
  unsigned short* Wh1P = us; us += PKS;
  unsigned short* Wi2P = us; us += PKS;
  unsigned short* Wh2P = us; us += PKS;
  // fp16 limb planes: [layer][buf][limb]
  unsigned short* L[3][2][2];
  for (int ly = 0; ly < 3; ++ly)
    for (int bu = 0; bu < 2; ++bu)
      for (int li = 0; li < 2; ++li) { L[ly][bu][li] = us; us += PLN; }
  float* p = (float*)us;
  // fp32 state planes: [layer][buf]
  float* F[3][2];
  for (int ly = 0; ly < 3; ++ly)
    for (int bu = 0; bu < 2; ++bu) { F[ly][bu] = p; p += PLN; }
  float* WiT0 = p; p += (size_t)DE * 3 * DH;
  float* G0   = p; p += (size_t)VOC * 3 * DH;
  float* z2hT = p; p += (size_t)DZ * DH;
  float* h2vP = p; p += (size_t)DH * VOC;
  int* tokb = (int*)p;
  int* eosb = tokb + NROWS;

  // one-time prep
  {
    int nblk = (int)(PKS / 256);
    pack_w2<<<nblk, 256, 0, stream>>>(W_hh0, Wh0P);
    pack_w2<<<nblk, 256, 0, stream>>>(W_ih1, Wi1P);
    pack_w2<<<nblk, 256, 0, stream>>>(W_hh1, Wh1P);
    pack_w2<<<nblk, 256, 0, stream>>>(W_ih2, Wi2P);
    pack_w2<<<nblk, 256, 0, stream>>>(W_hh2, Wh2P);
  }
  transpose_k<<<dim3(DE / 32, (3 * DH) / 32), dim3(32, 8), 0, stream>>>(
      W_ih0, WiT0, 3 * DH, DE);
  transpose_k<<<dim3(DZ / 32, DH / 32), dim3(32, 8), 0, stream>>>(
      z2h_w, z2hT, DH, DZ);
  repack_k<<<dim3(VOC, DH / 128), 128, 0, stream>>>(h2v_w, h2vP, VOC, DH);
  build_g0<<<dim3(VOC, (3 * DH) / 256), 256, 0, stream>>>(emb, WiT0, b_ih0, G0);

  init_kernel<<<dim3(NROWS / 4, DH / 64), 256, 0, stream>>>(
      Z, z2hT, z2h_b,
      L[0][0][0], L[0][0][1], F[0][0],
      L[1][0][0], L[1][0][1], F[1][0],
      L[2][0][0], L[2][0][1], F[2][0],
      tokb, eosb, outi);

  const int ggrid = (NROWS / 128) * 32;   // 1024 wgs, 4 per CU
  int cur = 0;
  for (int t = 1; t < MAXLEN; ++t) {
    int nxt = cur ^ 1;
    gru_mfma<true><<<ggrid, 256, 0, stream>>>(
        nullptr, nullptr,
        L[0][cur][0], L[0][cur][1], F[0][cur],
        nullptr, Wh0P, tokb, G0, nullptr, b_hh0,
        L[0][nxt][0], L[0][nxt][1], F[0][nxt]);
    gru_mfma<false><<<ggrid, 256, 0, stream>>>(
        L[0][nxt][0], L[0][nxt][1],
        L[1][cur][0], L[1][cur][1], F[1][cur],
        Wi1P, Wh1P, nullptr, nullptr, b_ih1, b_hh1,
        L[1][nxt][0], L[1][nxt][1], F[1][nxt]);
    gru_mfma<false><<<ggrid, 256, 0, stream>>>(
        L[1][nxt][0], L[1][nxt][1],
        L[2][cur][0], L[2][cur][1], F[2][cur],
        Wi2P, Wh2P, nullptr, nullptr, b_ih2, b_hh2,
        L[2][nxt][0], L[2][nxt][1], F[2][nxt]);
    argmax_kernel<<<dim3(NROWS / 16), 256, 0, stream>>>(
        F[2][nxt], h2vP, h2v_b, tokb, eosb, outi, t);
    cur = nxt;
  }
}

// Round 13
// 19945.244 us; speedup vs baseline: 2.9473x; 1.1007x over previous
//
#include <hip/hip_runtime.h>
#include <math.h>

#define NROWS 4096
#define DZ    128
#define DH    512
#define VOC   64
#define DE    128
#define MAXLEN 128
#define PAD_T 0
#define SOS_T 1
#define EOS_T 2

typedef __attribute__((ext_vector_type(8))) _Float16 f16x8;  // 8 f16 (4 VGPRs)
typedef __attribute__((ext_vector_type(4))) float f32x4;

__device__ __forceinline__ unsigned short hbits(_Float16 h) {
  return __builtin_bit_cast(unsigned short, h);
}
__device__ __forceinline__ f32x4 mfma_f16(f16x8 a, f16x8 b, f32x4 c) {
  return __builtin_amdgcn_mfma_f32_16x16x32_f16(a, b, c, 0, 0, 0);
}
#define GLD16(gp, lp)                                                        \
  __builtin_amdgcn_global_load_lds(                                          \
      (const __attribute__((address_space(1))) unsigned int*)(gp),           \
      (__attribute__((address_space(3))) unsigned int*)(lp), 16, 0, 0)

// A-fragment-major layout for activation limb planes:
// element (row, k) lives at ((row>>4)*16 + (k>>5))*512 + ((row&15) + 16*((k>>3)&3))*8 + (k&7)
__device__ __forceinline__ size_t PIDX(int row, int k) {
  return ((size_t)((row >> 4) * 16 + (k >> 5))) * 512 +
         (size_t)(((row & 15) + 16 * ((k >> 3) & 3)) * 8 + (k & 7));
}

// ---------------- transpose: in [R][C] -> out [C][R] ----------------
__global__ void transpose_k(const float* __restrict__ in, float* __restrict__ out,
                            int R, int C) {
  __shared__ float tile[32][33];
  int cb = blockIdx.x * 32, rb = blockIdx.y * 32;
  int tx = threadIdx.x, ty = threadIdx.y;  // blockDim (32,8)
  #pragma unroll
  for (int i = ty; i < 32; i += 8)
    tile[i][tx] = in[(size_t)(rb + i) * C + (cb + tx)];
  __syncthreads();
  #pragma unroll
  for (int i = ty; i < 32; i += 8)
    out[(size_t)(cb + i) * R + (rb + tx)] = tile[tx][i];
}

// ---------------- repack h2v: in [Rn][K] -> P[((k>>2)*Rn + r)*4 + (k&3)] -----
__global__ void repack_k(const float* __restrict__ in, float* __restrict__ out,
                         int Rn, int K) {
  int k = blockIdx.y * 128 + threadIdx.x;
  int r = blockIdx.x;
  out[((size_t)(k >> 2) * Rn + r) * 4 + (k & 3)] = in[(size_t)r * K + k];
}

// ---- pack weights to 2-limb fp16 B-fragments (m-limb scaled by 2^11) -------
// W [3*DH][512] fp32 -> out[g][l][nt][kc][lane][j] f16
__global__ void pack_w2(const float* __restrict__ W, unsigned short* __restrict__ out) {
  size_t i = (size_t)blockIdx.x * 256 + threadIdx.x;  // total 6*32*16*512
  int j = (int)(i & 7);
  int lane = (int)((i >> 3) & 63);
  size_t t = i >> 9;
  int kc = (int)(t & 15); t >>= 4;
  int nt = (int)(t & 31); t >>= 5;
  int l = (int)(t & 1);
  int g = (int)(t >> 1);
  int n = nt * 16 + (lane & 15);
  int k = kc * 32 + (lane >> 4) * 8 + j;
  float w = W[(size_t)(g * DH + n) * DH + k];
  _Float16 wh = (_Float16)w;
  float fh = (float)wh;
  _Float16 wm = (_Float16)((w - fh) * 2048.0f);
  out[i] = hbits(l == 0 ? wh : wm);
}

// ---------------- G0[v][jj] = sum_k emb[v][k] * WiT0[k][jj] + bi[jj] ---------
__global__ __launch_bounds__(256) void build_g0(
    const float* __restrict__ emb, const float* __restrict__ WiT0,
    const float* __restrict__ bi, float* __restrict__ G0) {
  int jj = blockIdx.y * 256 + threadIdx.x;   // grid.y = 3*DH/256
  int v = blockIdx.x;                        // grid.x = VOC
  float acc = bi[jj];
  const float* e = emb + (size_t)v * DE;     // wave-uniform -> s_load
  #pragma unroll 4
  for (int k = 0; k < DE; ++k)
    acc = fmaf(e[k], WiT0[(size_t)k * (3 * DH) + jj], acc);
  G0[(size_t)v * (3 * DH) + jj] = acc;
}

// ---------------- init: h0 = Z @ z2h_w^T + b; 2-limb + f32 state init --------
__global__ __launch_bounds__(256) void init_kernel(
    const float* __restrict__ Z, const float* __restrict__ z2hT,
    const float* __restrict__ z2h_b,
    unsigned short* __restrict__ h1H, unsigned short* __restrict__ h1M, float* __restrict__ f1,
    unsigned short* __restrict__ h2H, unsigned short* __restrict__ h2M, float* __restrict__ f2,
    unsigned short* __restrict__ h3H, unsigned short* __restrict__ h3M, float* __restrict__ f3,
    int* __restrict__ tok, int* __restrict__ eos, int* __restrict__ outi) {
  int lane = threadIdx.x & 63;
  int wave = __builtin_amdgcn_readfirstlane((int)(threadIdx.x >> 6));
  int r = blockIdx.x * 4 + wave;          // grid.x = NROWS/4
  int j = blockIdx.y * 64 + lane;         // grid.y = DH/64
  float acc = z2h_b[j];
  const float* zr = Z + (size_t)r * DZ;   // wave-uniform -> s_load
  #pragma unroll 4
  for (int k = 0; k < DZ; ++k)
    acc = fmaf(zr[k], z2hT[(size_t)k * DH + j], acc);
  size_t o = (size_t)r * DH + j;          // fp32 plane: plain layout
  size_t op = PIDX(r, j);                 // limb planes: fragment layout
  _Float16 uh = (_Float16)acc;
  float fh = (float)uh;
  _Float16 um = (_Float16)((acc - fh) * 2048.0f);
  unsigned short bh_ = hbits(uh), bm_ = hbits(um);
  h1H[op] = bh_; h1M[op] = bm_; f1[o] = acc;
  h2H[op] = bh_; h2M[op] = bm_; f2[o] = acc;
  h3H[op] = bh_; h3M[op] = bm_; f3[o] = acc;
  if (blockIdx.y == 0 && lane == 0) {
    tok[r] = SOS_T;
    eos[r] = 0;
    outi[(size_t)r * MAXLEN] = SOS_T;               // X_gen[:,0] = SOS
    outi[(size_t)NROWS * MAXLEN + r] = MAXLEN;      // seq_lens init
  }
}

// ---------------- fused GRU layer: fp16 2-limb MFMA + LDS-staged B ----------
// wg = 8 waves sharing one j-tile (512 thr); wave tile = 32 rows x 16 j x 3 g.
// B: global->LDS (GLD16) ping-pong 4-kc chunks (24 KB each, 48 KB total) ->
// 10 barriers/dispatch, 700-cyc compute window per chunk per wave.
// A: fragment-major limb planes -> one coalesced 1KB wave load per (mt,kc,limb).
template <bool IS_L0>
__global__ __launch_bounds__(512, 4) void gru_mfma(
    const unsigned short* __restrict__ XH, const unsigned short* __restrict__ XM,
    const unsigned short* __restrict__ HH, const unsigned short* __restrict__ HM,
    const float* __restrict__ Fin,           // prev h fp32 (blend), plain layout
    const unsigned short* __restrict__ WiPk, const unsigned short* __restrict__ WhPk,
    const int* __restrict__ tok, const float* __restrict__ G0,
    const float* __restrict__ bi, const float* __restrict__ bh,
    unsigned short* __restrict__ OH, unsigned short* __restrict__ OM,
    float* __restrict__ Fout) {
  __shared__ __attribute__((aligned(16))) unsigned short ldsB[2][24 * 512]; // 48 KB
  const int tid  = threadIdx.x;
  const int lane = tid & 63;
  const int wave = __builtin_amdgcn_readfirstlane(tid >> 6);  // 0..7
  const int wg = blockIdx.x;
  const int ntile = wg & 31;           // j-tile
  const int rblk = wg >> 5;            // row block; grid.x = (NROWS/256)*32
  const int m0 = rblk * 256 + wave * 32;
  const int rt0 = (m0 >> 4);           // row-tile index for A-fragment layout
  const int col = lane & 15, quad = lane >> 4;
  const int jc = ntile * 16 + col;

  f32x4 accH[2][4], accC[2][4];        // [mt][plane: r,z,in,hn]
  #pragma unroll
  for (int mt = 0; mt < 2; ++mt)
    #pragma unroll
    for (int p = 0; p < 4; ++p) {
      accH[mt][p] = (f32x4){0.f, 0.f, 0.f, 0.f};
      accC[mt][p] = (f32x4){0.f, 0.f, 0.f, 0.f};
    }

  // stage chunk c (kc = 4c..4c+3): 24 segs (kci*6 + g*2 + l), split over 8 waves
  auto stage = [&](const unsigned short* Wp, int c, int buf) {
    for (int s = wave; s < 24; s += 8) {
      int kci = s / 6, gl = s - 6 * kci;
      const unsigned short* src =
          Wp + (((size_t)gl * 32 + ntile) * 16 + (c * 4 + kci)) * 512 + lane * 8;
      GLD16(src, &ldsB[buf][(size_t)s * 512]);
    }
  };

  auto phase = [&](const unsigned short* AH, const unsigned short* AM,
                   const unsigned short* Wp, int nplane) {
    stage(Wp, 0, 0);
    for (int c = 0; c < 4; ++c) {
      __syncthreads();                       // drains staging of chunk c
      if (c + 1 < 4) stage(Wp, c + 1, (c + 1) & 1);
      const unsigned short* S = ldsB[c & 1];
      #pragma unroll
      for (int kc2 = 0; kc2 < 4; ++kc2) {
        int kc = c * 4 + kc2;
        f16x8 a0[2], a1[2];
        #pragma unroll
        for (int mt = 0; mt < 2; ++mt) {
          // fragment-major: one coalesced 1KB wave load per limb
          size_t ao = ((size_t)(rt0 + mt) * 16 + kc) * 512 + (size_t)lane * 8;
          a0[mt] = *(const f16x8*)(AH + ao);
          a1[mt] = *(const f16x8*)(AM + ao);
        }
        #pragma unroll
        for (int g = 0; g < 3; ++g) {
          const unsigned short* bp = S + (size_t)(kc2 * 6 + g * 2) * 512 + lane * 8;
          f16x8 b0 = *(const f16x8*)(bp);            // limb h
          f16x8 b1 = *(const f16x8*)(bp + 512);      // limb m (x2048)
          int pl = (g == 2) ? nplane : g;
          #pragma unroll
          for (int mt = 0; mt < 2; ++mt) {
            accC[mt][pl] = mfma_f16(a1[mt], b0, accC[mt][pl]);  // am*wh
            accC[mt][pl] = mfma_f16(a0[mt], b1, accC[mt][pl]);  // ah*wm
            accH[mt][pl] = mfma_f16(a0[mt], b0, accH[mt][pl]);  // ah*wh
          }
        }
      }
    }
    __syncthreads();                           // protect LDS before next phase
  };

  if constexpr (!IS_L0)
    phase(XH, XM, WiPk, 2);
  phase(HH, HM, WhPk, 3);

  float bhr = bh[jc], bhz = bh[DH + jc], bhn = bh[2 * DH + jc];
  float bir = 0.f, biz = 0.f, bin = 0.f;
  if constexpr (!IS_L0) { bir = bi[jc]; biz = bi[DH + jc]; bin = bi[2 * DH + jc]; }
  const float IS = 1.0f / 2048.0f;

  #pragma unroll
  for (int mt = 0; mt < 2; ++mt) {
    #pragma unroll
    for (int i = 0; i < 4; ++i) {
      int row = m0 + mt * 16 + quad * 4 + i;
      float gr = accH[mt][0][i] + IS * accC[mt][0][i] + bhr;
      float gz = accH[mt][1][i] + IS * accC[mt][1][i] + bhz;
      float gin = accH[mt][2][i] + IS * accC[mt][2][i];
      float ghn = accH[mt][3][i] + IS * accC[mt][3][i] + bhn;
      if constexpr (IS_L0) {
        const float* g0p = G0 + (size_t)tok[row] * (3 * DH);
        gr += g0p[jc]; gz += g0p[DH + jc]; gin += g0p[2 * DH + jc];
      } else {
        gr += bir; gz += biz; gin += bin;
      }
      float rg = 1.f / (1.f + expf(-gr));
      float zg = 1.f / (1.f + expf(-gz));
      float nn = tanhf(gin + rg * ghn);
      size_t ho = (size_t)row * DH + jc;        // fp32 plane: plain
      float hp = Fin[ho];                       // exact fp32 prev state
      float hv = (1.f - zg) * nn + zg * hp;
      _Float16 uh = (_Float16)hv;
      float fh = (float)uh;
      _Float16 um = (_Float16)((hv - fh) * 2048.0f);
      size_t hop = PIDX(row, jc);               // limb planes: fragment layout
      OH[hop] = hbits(uh); OM[hop] = hbits(um);
      Fout[ho] = hv;
    }
  }
}

// ---------------- logits + argmax + EOS bookkeeping ----------------
__global__ __launch_bounds__(256) void argmax_kernel(
    const float* __restrict__ H3, const float* __restrict__ h2vP,
    const float* __restrict__ h2v_b,
    int* __restrict__ tok, int* __restrict__ eos,
    int* __restrict__ outi, int t) {
  int lane = threadIdx.x & 63;
  int wave = __builtin_amdgcn_readfirstlane((int)(threadIdx.x >> 6));
  int r0 = blockIdx.x * 16 + wave * 4;    // grid.x = NROWS/16
  float acc[4];
  float b = h2v_b[lane];
  #pragma unroll
  for (int i = 0; i < 4; ++i) acc[i] = b;
  const float4* w4 = (const float4*)h2vP;
  const float4* h4[4];
  #pragma unroll
  for (int i = 0; i < 4; ++i)
    h4[i] = (const float4*)(H3 + (size_t)(r0 + i) * DH);
  #pragma unroll 2
  for (int k4 = 0; k4 < DH / 4; ++k4) {
    float4 w = w4[(size_t)k4 * VOC + lane];       // coalesced vector
    #pragma unroll
    for (int i = 0; i < 4; ++i) {
      float4 h = h4[i][k4];                        // wave-uniform -> s_load
      acc[i] = fmaf(h.x, w.x, acc[i]); acc[i] = fmaf(h.y, w.y, acc[i]);
      acc[i] = fmaf(h.z, w.z, acc[i]); acc[i] = fmaf(h.w, w.w, acc[i]);
    }
  }
  #pragma unroll
  for (int i = 0; i < 4; ++i) {
    float v = acc[i]; int idx = lane;
    #pragma unroll
    for (int off = 32; off >= 1; off >>= 1) {
      float v2 = __shfl_xor(v, off);
      int   i2 = __shfl_xor(idx, off);
      if (v2 > v || (v2 == v && i2 < idx)) { v = v2; idx = i2; }
    }
    if (lane == 0) {
      int r = r0 + i;
      int e = eos[r];
      int x_next = idx;
      outi[(size_t)r * MAXLEN + t] = e ? PAD_T : x_next;
      if (!e && x_next == EOS_T) {
        outi[(size_t)NROWS * MAXLEN + r] = t + 1;  // seq_lens
        eos[r] = 1;
      }
      tok[r] = x_next;
    }
  }
}

// ---------------- host-side orchestration ----------------
extern "C" void kernel_launch(void* const* d_in, const int* in_sizes, int n_in,
                              void* d_out, int out_size, void* d_ws, size_t ws_size,
                              hipStream_t stream) {
  const float* Z      = (const float*)d_in[0];
  const float* emb    = (const float*)d_in[1];
  const float* z2h_w  = (const float*)d_in[2];
  const float* z2h_b  = (const float*)d_in[3];
  const float* W_ih0  = (const float*)d_in[4];
  const float* W_hh0  = (const float*)d_in[5];
  const float* b_ih0  = (const float*)d_in[6];
  const float* b_hh0  = (const float*)d_in[7];
  const float* W_ih1  = (const float*)d_in[8];
  const float* W_hh1  = (const float*)d_in[9];
  const float* b_ih1  = (const float*)d_in[10];
  const float* b_hh1  = (const float*)d_in[11];
  const float* W_ih2  = (const float*)d_in[12];
  const float* W_hh2  = (const float*)d_in[13];
  const float* b_ih2  = (const float*)d_in[14];
  const float* b_hh2  = (const float*)d_in[15];
  const float* h2v_w  = (const float*)d_in[16];
  const float* h2v_b  = (const float*)d_in[17];
  int* outi = (int*)d_out;

  const size_t PKS = (size_t)6 * 32 * 16 * 512;   // ushorts per packed matrix
  const size_t PLN = (size_t)NROWS * DH;          // elems per state plane

  unsigned short* us = (unsigned short*)d_ws;
  unsigned short* Wh0P = us; us += PKS;
  unsigned short* Wi1P = us; us += PKS;
  unsigned short* Wh1P = us; us += PKS;
  unsigned short* Wi2P = us; us += PKS;
  unsigned short* Wh2P = us; us += PKS;
  // fp16 limb planes: [layer][buf][limb]
  unsigned short* L[3][2][2];
  for (int ly = 0; ly < 3; ++ly)
    for (int bu = 0; bu < 2; ++bu)
      for (int li = 0; li < 2; ++li) { L[ly][bu][li] = us; us += PLN; }
  float* p = (float*)us;
  // fp32 state planes: [layer][buf]
  float* F[3][2];
  for (int ly = 0; ly < 3; ++ly)
    for (int bu = 0; bu < 2; ++bu) { F[ly][bu] = p; p += PLN; }
  float* WiT0 = p; p += (size_t)DE * 3 * DH;
  float* G0   = p; p += (size_t)VOC * 3 * DH;
  float* z2hT = p; p += (size_t)DZ * DH;
  float* h2vP = p; p += (size_t)DH * VOC;
  int* tokb = (int*)p;
  int* eosb = tokb + NROWS;

  // one-time prep
  {
    int nblk = (int)(PKS / 256);
    pack_w2<<<nblk, 256, 0, stream>>>(W_hh0, Wh0P);
    pack_w2<<<nblk, 256, 0, stream>>>(W_ih1, Wi1P);
    pack_w2<<<nblk, 256, 0, stream>>>(W_hh1, Wh1P);
    pack_w2<<<nblk, 256, 0, stream>>>(W_ih2, Wi2P);
    pack_w2<<<nblk, 256, 0, stream>>>(W_hh2, Wh2P);
  }
  transpose_k<<<dim3(DE / 32, (3 * DH) / 32), dim3(32, 8), 0, stream>>>(
      W_ih0, WiT0, 3 * DH, DE);
  transpose_k<<<dim3(DZ / 32, DH / 32), dim3(32, 8), 0, stream>>>(
      z2h_w, z2hT, DH, DZ);
  repack_k<<<dim3(VOC, DH / 128), 128, 0, stream>>>(h2v_w, h2vP, VOC, DH);
  build_g0<<<dim3(VOC, (3 * DH) / 256), 256, 0, stream>>>(emb, WiT0, b_ih0, G0);

  init_kernel<<<dim3(NROWS / 4, DH / 64), 256, 0, stream>>>(
      Z, z2hT, z2h_b,
      L[0][0][0], L[0][0][1], F[0][0],
      L[1][0][0], L[1][0][1], F[1][0],
      L[2][0][0], L[2][0][1], F[2][0],
      tokb, eosb, outi);

  const int ggrid = (NROWS / 256) * 32;   // 512 wgs of 512 thr, 2 per CU
  int cur = 0;
  for (int t = 1; t < MAXLEN; ++t) {
    int nxt = cur ^ 1;
    gru_mfma<true><<<ggrid, 512, 0, stream>>>(
        nullptr, nullptr,
        L[0][cur][0], L[0][cur][1], F[0][cur],
        nullptr, Wh0P, tokb, G0, nullptr, b_hh0,
        L[0][nxt][0], L[0][nxt][1], F[0][nxt]);
    gru_mfma<false><<<ggrid, 512, 0, stream>>>(
        L[0][nxt][0], L[0][nxt][1],
        L[1][cur][0], L[1][cur][1], F[1][cur],
        Wi1P, Wh1P, nullptr, nullptr, b_ih1, b_hh1,
        L[1][nxt][0], L[1][nxt][1], F[1][nxt]);
    gru_mfma<false><<<ggrid, 512, 0, stream>>>(
        L[1][nxt][0], L[1][nxt][1],
        L[2][cur][0], L[2][cur][1], F[2][cur],
        Wi2P, Wh2P, nullptr, nullptr, b_ih2, b_hh2,
        L[2][nxt][0], L[2][nxt][1], F[2][nxt]);
    argmax_kernel<<<dim3(NROWS / 16), 256, 0, stream>>>(
        F[2][nxt], h2vP, h2v_b, tokb, eosb, outi, t);
    cur = nxt;
  }
}

// Round 14
// 19212.169 us; speedup vs baseline: 3.0598x; 1.0382x over previous
//
#include <hip/hip_runtime.h>
#include <math.h>

#define NROWS 4096
#define DZ    128
#define DH    512
#define VOC   64
#define DE    128
#define MAXLEN 128
#define PAD_T 0
#define SOS_T 1
#define EOS_T 2

typedef __attribute__((ext_vector_type(8))) _Float16 f16x8;  // 8 f16 (4 VGPRs)
typedef __attribute__((ext_vector_type(4))) float f32x4;

__device__ __forceinline__ unsigned short hbits(_Float16 h) {
  return __builtin_bit_cast(unsigned short, h);
}
__device__ __forceinline__ f32x4 mfma_f16(f16x8 a, f16x8 b, f32x4 c) {
  return __builtin_amdgcn_mfma_f32_16x16x32_f16(a, b, c, 0, 0, 0);
}
#define GLD16(gp, lp)                                                        \
  __builtin_amdgcn_global_load_lds(                                          \
      (const __attribute__((address_space(1))) unsigned int*)(gp),           \
      (__attribute__((address_space(3))) unsigned int*)(lp), 16, 0, 0)

// A-fragment-major layout for activation limb planes:
// element (row, k) lives at ((row>>4)*16 + (k>>5))*512 + ((row&15) + 16*((k>>3)&3))*8 + (k&7)
__device__ __forceinline__ size_t PIDX(int row, int k) {
  return ((size_t)((row >> 4) * 16 + (k >> 5))) * 512 +
         (size_t)(((row & 15) + 16 * ((k >> 3) & 3)) * 8 + (k & 7));
}

// ---------------- transpose: in [R][C] -> out [C][R] ----------------
__global__ void transpose_k(const float* __restrict__ in, float* __restrict__ out,
                            int R, int C) {
  __shared__ float tile[32][33];
  int cb = blockIdx.x * 32, rb = blockIdx.y * 32;
  int tx = threadIdx.x, ty = threadIdx.y;  // blockDim (32,8)
  #pragma unroll
  for (int i = ty; i < 32; i += 8)
    tile[i][tx] = in[(size_t)(rb + i) * C + (cb + tx)];
  __syncthreads();
  #pragma unroll
  for (int i = ty; i < 32; i += 8)
    out[(size_t)(cb + i) * R + (rb + tx)] = tile[tx][i];
}

// ---------------- repack h2v: in [Rn][K] -> P[((k>>2)*Rn + r)*4 + (k&3)] -----
__global__ void repack_k(const float* __restrict__ in, float* __restrict__ out,
                         int Rn, int K) {
  int k = blockIdx.y * 128 + threadIdx.x;
  int r = blockIdx.x;
  out[((size_t)(k >> 2) * Rn + r) * 4 + (k & 3)] = in[(size_t)r * K + k];
}

// ---- pack weights to 2-limb fp16 B-fragments (m-limb scaled by 2^11) -------
// W [3*DH][512] fp32 -> out[g][l][nt][kc][lane][j] f16
__global__ void pack_w2(const float* __restrict__ W, unsigned short* __restrict__ out) {
  size_t i = (size_t)blockIdx.x * 256 + threadIdx.x;  // total 6*32*16*512
  int j = (int)(i & 7);
  int lane = (int)((i >> 3) & 63);
  size_t t = i >> 9;
  int kc = (int)(t & 15); t >>= 4;
  int nt = (int)(t & 31); t >>= 5;
  int l = (int)(t & 1);
  int g = (int)(t >> 1);
  int n = nt * 16 + (lane & 15);
  int k = kc * 32 + (lane >> 4) * 8 + j;
  float w = W[(size_t)(g * DH + n) * DH + k];
  _Float16 wh = (_Float16)w;
  float fh = (float)wh;
  _Float16 wm = (_Float16)((w - fh) * 2048.0f);
  out[i] = hbits(l == 0 ? wh : wm);
}

// ---------------- G0[v][jj] = sum_k emb[v][k] * WiT0[k][jj] + bi[jj] ---------
__global__ __launch_bounds__(256) void build_g0(
    const float* __restrict__ emb, const float* __restrict__ WiT0,
    const float* __restrict__ bi, float* __restrict__ G0) {
  int jj = blockIdx.y * 256 + threadIdx.x;   // grid.y = 3*DH/256
  int v = blockIdx.x;                        // grid.x = VOC
  float acc = bi[jj];
  const float* e = emb + (size_t)v * DE;     // wave-uniform -> s_load
  #pragma unroll 4
  for (int k = 0; k < DE; ++k)
    acc = fmaf(e[k], WiT0[(size_t)k * (3 * DH) + jj], acc);
  G0[(size_t)v * (3 * DH) + jj] = acc;
}

// ---------------- init: h0 = Z @ z2h_w^T + b; 2-limb + f32 state init --------
__global__ __launch_bounds__(256) void init_kernel(
    const float* __restrict__ Z, const float* __restrict__ z2hT,
    const float* __restrict__ z2h_b,
    unsigned short* __restrict__ h1H, unsigned short* __restrict__ h1M, float* __restrict__ f1,
    unsigned short* __restrict__ h2H, unsigned short* __restrict__ h2M, float* __restrict__ f2,
    unsigned short* __restrict__ h3H, unsigned short* __restrict__ h3M, float* __restrict__ f3,
    int* __restrict__ tok, int* __restrict__ eos, int* __restrict__ outi) {
  int lane = threadIdx.x & 63;
  int wave = __builtin_amdgcn_readfirstlane((int)(threadIdx.x >> 6));
  int r = blockIdx.x * 4 + wave;          // grid.x = NROWS/4
  int j = blockIdx.y * 64 + lane;         // grid.y = DH/64
  float acc = z2h_b[j];
  const float* zr = Z + (size_t)r * DZ;   // wave-uniform -> s_load
  #pragma unroll 4
  for (int k = 0; k < DZ; ++k)
    acc = fmaf(zr[k], z2hT[(size_t)k * DH + j], acc);
  size_t o = (size_t)r * DH + j;          // fp32 plane: plain layout
  size_t op = PIDX(r, j);                 // limb planes: fragment layout
  _Float16 uh = (_Float16)acc;
  float fh = (float)uh;
  _Float16 um = (_Float16)((acc - fh) * 2048.0f);
  unsigned short bh_ = hbits(uh), bm_ = hbits(um);
  h1H[op] = bh_; h1M[op] = bm_; f1[o] = acc;
  h2H[op] = bh_; h2M[op] = bm_; f2[o] = acc;
  h3H[op] = bh_; h3M[op] = bm_; f3[o] = acc;
  if (blockIdx.y == 0 && lane == 0) {
    tok[r] = SOS_T;
    eos[r] = 0;
    outi[(size_t)r * MAXLEN] = SOS_T;               // X_gen[:,0] = SOS
    outi[(size_t)NROWS * MAXLEN + r] = MAXLEN;      // seq_lens init
  }
}

// ---------------- fused GRU layer: fp16 2-limb MFMA + LDS-staged B ----------
// wg = 8 waves sharing one j-tile (512 thr); wave tile = 32 rows x 16 j x 3 g.
// Grid decode rblk = wg&15, ntile = wg>>4: with round-robin wg->XCD (%8),
// all 32 wgs of a row-block land on one XCD -> A is XCD-L2-resident
// (2 MB/XCD), A-load latency ~200cyc, hidden in the 700-cyc chunk window.
// B: global->LDS (GLD16) ping-pong 4-kc chunks (24 KB each, 48 KB total).
template <bool IS_L0>
__global__ __launch_bounds__(512, 4) void gru_mfma(
    const unsigned short* __restrict__ XH, const unsigned short* __restrict__ XM,
    const unsigned short* __restrict__ HH, const unsigned short* __restrict__ HM,
    const float* __restrict__ Fin,           // prev h fp32 (blend), plain layout
    const unsigned short* __restrict__ WiPk, const unsigned short* __restrict__ WhPk,
    const int* __restrict__ tok, const float* __restrict__ G0,
    const float* __restrict__ bi, const float* __restrict__ bh,
    unsigned short* __restrict__ OH, unsigned short* __restrict__ OM,
    float* __restrict__ Fout) {
  __shared__ __attribute__((aligned(16))) unsigned short ldsB[2][24 * 512]; // 48 KB
  const int tid  = threadIdx.x;
  const int lane = tid & 63;
  const int wave = __builtin_amdgcn_readfirstlane(tid >> 6);  // 0..7
  const int wg = blockIdx.x;
  const int rblk  = wg & 15;           // row block -> XCD-local A
  const int ntile = wg >> 4;           // j-tile; grid.x = 16*32
  const int m0 = rblk * 256 + wave * 32;
  const int rt0 = (m0 >> 4);           // row-tile index for A-fragment layout
  const int col = lane & 15, quad = lane >> 4;
  const int jc = ntile * 16 + col;

  f32x4 accH[2][4], accC[2][4];        // [mt][plane: r,z,in,hn]
  #pragma unroll
  for (int mt = 0; mt < 2; ++mt)
    #pragma unroll
    for (int p = 0; p < 4; ++p) {
      accH[mt][p] = (f32x4){0.f, 0.f, 0.f, 0.f};
      accC[mt][p] = (f32x4){0.f, 0.f, 0.f, 0.f};
    }

  // stage chunk c (kc = 4c..4c+3): 24 segs (kci*6 + g*2 + l), split over 8 waves
  auto stage = [&](const unsigned short* Wp, int c, int buf) {
    for (int s = wave; s < 24; s += 8) {
      int kci = s / 6, gl = s - 6 * kci;
      const unsigned short* src =
          Wp + (((size_t)gl * 32 + ntile) * 16 + (c * 4 + kci)) * 512 + lane * 8;
      GLD16(src, &ldsB[buf][(size_t)s * 512]);
    }
  };

  auto phase = [&](const unsigned short* AH, const unsigned short* AM,
                   const unsigned short* Wp, int nplane) {
    stage(Wp, 0, 0);
    for (int c = 0; c < 4; ++c) {
      __syncthreads();                       // drains staging of chunk c
      if (c + 1 < 4) stage(Wp, c + 1, (c + 1) & 1);
      const unsigned short* S = ldsB[c & 1];
      #pragma unroll
      for (int kc2 = 0; kc2 < 4; ++kc2) {
        int kc = c * 4 + kc2;
        f16x8 a0[2], a1[2];
        #pragma unroll
        for (int mt = 0; mt < 2; ++mt) {
          // fragment-major: one coalesced 1KB wave load per limb
          size_t ao = ((size_t)(rt0 + mt) * 16 + kc) * 512 + (size_t)lane * 8;
          a0[mt] = *(const f16x8*)(AH + ao);
          a1[mt] = *(const f16x8*)(AM + ao);
        }
        #pragma unroll
        for (int g = 0; g < 3; ++g) {
          const unsigned short* bp = S + (size_t)(kc2 * 6 + g * 2) * 512 + lane * 8;
          f16x8 b0 = *(const f16x8*)(bp);            // limb h
          f16x8 b1 = *(const f16x8*)(bp + 512);      // limb m (x2048)
          int pl = (g == 2) ? nplane : g;
          #pragma unroll
          for (int mt = 0; mt < 2; ++mt) {
            accC[mt][pl] = mfma_f16(a1[mt], b0, accC[mt][pl]);  // am*wh
            accC[mt][pl] = mfma_f16(a0[mt], b1, accC[mt][pl]);  // ah*wm
            accH[mt][pl] = mfma_f16(a0[mt], b0, accH[mt][pl]);  // ah*wh
          }
        }
      }
    }
    __syncthreads();                           // protect LDS before next phase
  };

  if constexpr (!IS_L0)
    phase(XH, XM, WiPk, 2);
  phase(HH, HM, WhPk, 3);

  float bhr = bh[jc], bhz = bh[DH + jc], bhn = bh[2 * DH + jc];
  float bir = 0.f, biz = 0.f, bin = 0.f;
  if constexpr (!IS_L0) { bir = bi[jc]; biz = bi[DH + jc]; bin = bi[2 * DH + jc]; }
  const float IS = 1.0f / 2048.0f;

  #pragma unroll
  for (int mt = 0; mt < 2; ++mt) {
    #pragma unroll
    for (int i = 0; i < 4; ++i) {
      int row = m0 + mt * 16 + quad * 4 + i;
      float gr = accH[mt][0][i] + IS * accC[mt][0][i] + bhr;
      float gz = accH[mt][1][i] + IS * accC[mt][1][i] + bhz;
      float gin = accH[mt][2][i] + IS * accC[mt][2][i];
      float ghn = accH[mt][3][i] + IS * accC[mt][3][i] + bhn;
      if constexpr (IS_L0) {
        const float* g0p = G0 + (size_t)tok[row] * (3 * DH);
        gr += g0p[jc]; gz += g0p[DH + jc]; gin += g0p[2 * DH + jc];
      } else {
        gr += bir; gz += biz; gin += bin;
      }
      float rg = 1.f / (1.f + expf(-gr));
      float zg = 1.f / (1.f + expf(-gz));
      float nn = tanhf(gin + rg * ghn);
      size_t ho = (size_t)row * DH + jc;        // fp32 plane: plain
      float hp = Fin[ho];                       // exact fp32 prev state
      float hv = (1.f - zg) * nn + zg * hp;
      _Float16 uh = (_Float16)hv;
      float fh = (float)uh;
      _Float16 um = (_Float16)((hv - fh) * 2048.0f);
      size_t hop = PIDX(row, jc);               // limb planes: fragment layout
      OH[hop] = hbits(uh); OM[hop] = hbits(um);
      Fout[ho] = hv;
    }
  }
}

// ---------------- logits + argmax + EOS bookkeeping ----------------
// wave -> 2 rows (grid 512 wgs for latency), lane = vocab id
__global__ __launch_bounds__(256) void argmax_kernel(
    const float* __restrict__ H3, const float* __restrict__ h2vP,
    const float* __restrict__ h2v_b,
    int* __restrict__ tok, int* __restrict__ eos,
    int* __restrict__ outi, int t) {
  int lane = threadIdx.x & 63;
  int wave = __builtin_amdgcn_readfirstlane((int)(threadIdx.x >> 6));
  int r0 = blockIdx.x * 8 + wave * 2;     // grid.x = NROWS/8
  float acc[2];
  float b = h2v_b[lane];
  #pragma unroll
  for (int i = 0; i < 2; ++i) acc[i] = b;
  const float4* w4 = (const float4*)h2vP;
  const float4* h4[2];
  #pragma unroll
  for (int i = 0; i < 2; ++i)
    h4[i] = (const float4*)(H3 + (size_t)(r0 + i) * DH);
  #pragma unroll 2
  for (int k4 = 0; k4 < DH / 4; ++k4) {
    float4 w = w4[(size_t)k4 * VOC + lane];       // coalesced vector
    #pragma unroll
    for (int i = 0; i < 2; ++i) {
      float4 h = h4[i][k4];                        // wave-uniform -> s_load
      acc[i] = fmaf(h.x, w.x, acc[i]); acc[i] = fmaf(h.y, w.y, acc[i]);
      acc[i] = fmaf(h.z, w.z, acc[i]); acc[i] = fmaf(h.w, w.w, acc[i]);
    }
  }
  #pragma unroll
  for (int i = 0; i < 2; ++i) {
    float v = acc[i]; int idx = lane;
    #pragma unroll
    for (int off = 32; off >= 1; off >>= 1) {
      float v2 = __shfl_xor(v, off);
      int   i2 = __shfl_xor(idx, off);
      if (v2 > v || (v2 == v && i2 < idx)) { v = v2; idx = i2; }
    }
    if (lane == 0) {
      int r = r0 + i;
      int e = eos[r];
      int x_next = idx;
      outi[(size_t)r * MAXLEN + t] = e ? PAD_T : x_next;
      if (!e && x_next == EOS_T) {
        outi[(size_t)NROWS * MAXLEN + r] = t + 1;  // seq_lens
        eos[r] = 1;
      }
      tok[r] = x_next;
    }
  }
}

// ---------------- host-side orchestration ----------------
extern "C" void kernel_launch(void* const* d_in, const int* in_sizes, int n_in,
                              void* d_out, int out_size, void* d_ws, size_t ws_size,
                              hipStream_t stream) {
  const float* Z      = (const float*)d_in[0];
  const float* emb    = (const float*)d_in[1];
  const float* z2h_w  = (const float*)d_in[2];
  const float* z2h_b  = (const float*)d_in[3];
  const float* W_ih0  = (const float*)d_in[4];
  const float* W_hh0  = (const float*)d_in[5];
  const float* b_ih0  = (const float*)d_in[6];
  const float* b_hh0  = (const float*)d_in[7];
  const float* W_ih1  = (const float*)d_in[8];
  const float* W_hh1  = (const float*)d_in[9];
  const float* b_ih1  = (const float*)d_in[10];
  const float* b_hh1  = (const float*)d_in[11];
  const float* W_ih2  = (const float*)d_in[12];
  const float* W_hh2  = (const float*)d_in[13];
  const float* b_ih2  = (const float*)d_in[14];
  const float* b_hh2  = (const float*)d_in[15];
  const float* h2v_w  = (const float*)d_in[16];
  const float* h2v_b  = (const float*)d_in[17];
  int* outi = (int*)d_out;

  const size_t PKS = (size_t)6 * 32 * 16 * 512;   // ushorts per packed matrix
  const size_t PLN = (size_t)NROWS * DH;          // elems per state plane

  unsigned short* us = (unsigned short*)d_ws;
  unsigned short* Wh0P = us; us += PKS;
  unsigned short* Wi1P = us; us += PKS;
  unsigned short* Wh1P = us; us += PKS;
  unsigned short* Wi2P = us; us += PKS;
  unsigned short* Wh2P = us; us += PKS;
  // fp16 limb planes: [layer][buf][limb]
  unsigned short* L[3][2][2];
  for (int ly = 0; ly < 3; ++ly)
    for (int bu = 0; bu < 2; ++bu)
      for (int li = 0; li < 2; ++li) { L[ly][bu][li] = us; us += PLN; }
  float* p = (float*)us;
  // fp32 state planes: [layer][buf]
  float* F[3][2];
  for (int ly = 0; ly < 3; ++ly)
    for (int bu = 0; bu < 2; ++bu) { F[ly][bu] = p; p += PLN; }
  float* WiT0 = p; p += (size_t)DE * 3 * DH;
  float* G0   = p; p += (size_t)VOC * 3 * DH;
  float* z2hT = p; p += (size_t)DZ * DH;
  float* h2vP = p; p += (size_t)DH * VOC;
  int* tokb = (int*)p;
  int* eosb = tokb + NROWS;

  // one-time prep
  {
    int nblk = (int)(PKS / 256);
    pack_w2<<<nblk, 256, 0, stream>>>(W_hh0, Wh0P);
    pack_w2<<<nblk, 256, 0, stream>>>(W_ih1, Wi1P);
    pack_w2<<<nblk, 256, 0, stream>>>(W_hh1, Wh1P);
    pack_w2<<<nblk, 256, 0, stream>>>(W_ih2, Wi2P);
    pack_w2<<<nblk, 256, 0, stream>>>(W_hh2, Wh2P);
  }
  transpose_k<<<dim3(DE / 32, (3 * DH) / 32), dim3(32, 8), 0, stream>>>(
      W_ih0, WiT0, 3 * DH, DE);
  transpose_k<<<dim3(DZ / 32, DH / 32), dim3(32, 8), 0, stream>>>(
      z2h_w, z2hT, DH, DZ);
  repack_k<<<dim3(VOC, DH / 128), 128, 0, stream>>>(h2v_w, h2vP, VOC, DH);
  build_g0<<<dim3(VOC, (3 * DH) / 256), 256, 0, stream>>>(emb, WiT0, b_ih0, G0);

  init_kernel<<<dim3(NROWS / 4, DH / 64), 256, 0, stream>>>(
      Z, z2hT, z2h_b,
      L[0][0][0], L[0][0][1], F[0][0],
      L[1][0][0], L[1][0][1], F[1][0],
      L[2][0][0], L[2][0][1], F[2][0],
      tokb, eosb, outi);

  const int ggrid = 16 * 32;   // 512 wgs of 512 thr, 2 per CU
  int cur = 0;
  for (int t = 1; t < MAXLEN; ++t) {
    int nxt = cur ^ 1;
    gru_mfma<true><<<ggrid, 512, 0, stream>>>(
        nullptr, nullptr,
        L[0][cur][0], L[0][cur][1], F[0][cur],
        nullptr, Wh0P, tokb, G0, nullptr, b_hh0,
        L[0][nxt][0], L[0][nxt][1], F[0][nxt]);
    gru_mfma<false><<<ggrid, 512, 0, stream>>>(
        L[0][nxt][0], L[0][nxt][1],
        L[1][cur][0], L[1][cur][1], F[1][cur],
        Wi1P, Wh1P, nullptr, nullptr, b_ih1, b_hh1,
        L[1][nxt][0], L[1][nxt][1], F[1][nxt]);
    gru_mfma<false><<<ggrid, 512, 0, stream>>>(
        L[1][nxt][0], L[1][nxt][1],
        L[2][cur][0], L[2][cur][1], F[2][cur],
        Wi2P, Wh2P, nullptr, nullptr, b_ih2, b_hh2,
        L[2][nxt][0], L[2][nxt][1], F[2][nxt]);
    argmax_kernel<<<dim3(NROWS / 8), 256, 0, stream>>>(
        F[2][nxt], h2vP, h2v_b, tokb, eosb, outi, t);
    cur = nxt;
  }
}